// Round 14
// baseline (28.576 us; speedup 1.0000x reference)
//
#include <hip/hip_runtime.h>
#include <math.h>

#define NB 768
#define ND 128
#define NC 12            // NB / 64 lane-chunks (mining layout)
#define APB 3            // anchors per block -> 256 blocks
#define NTH 768          // 12 waves per block
#define TL_MARGIN 1.0f
#define TL_EPS 1e-12f

// ws layout (bytes):
//   ET   @ 0x00000 : 128*768 f32 = 384 KB   (ET[k][j] = E[j][k])
//   psum @ 0x60000 : 768 f32
//   pcnt @ 0x60C00 : 768 f32

// ---- K0: pure transpose, coalesced ET writes; 384 blocks x 256 thr ----
__global__ __launch_bounds__(256) void transpose_kernel(
    const float* __restrict__ E, float* __restrict__ ET)
{
    const int b   = blockIdx.x;           // 0..383
    const int tid = threadIdx.x;
    const int k   = b / 3;                // uniform per block
    const int j   = (b % 3) * 256 + tid;  // lanes consecutive j
    ET[(size_t)k * NB + j] = E[(size_t)j * ND + k];  // write: full coalesced lines
}

// ---- K1: fused distance (split-k) + mining (4-way split); 256 x 768 ----
__global__ __launch_bounds__(NTH) void triplet_fused_kernel(
    const float* __restrict__ E, const float* __restrict__ ET,
    const int* __restrict__ L,
    float* __restrict__ psum, float* __restrict__ pcnt)
{
    __shared__ float drowp[2][APB][NB];    // 18 KB : per-k-half (sj - 2*dot)
    __shared__ float wsum[12], wcnt[12];

    const int tid  = threadIdx.x;
    const int lane = tid & 63;
    const int wave = tid >> 6;             // 0..11
    int i0 = blockIdx.x * APB;
    i0 = __builtin_amdgcn_readfirstlane(i0);

    // anchor rows via wave-uniform pointers -> scalar (SGPR) loads
    const float* __restrict__ A0 = E + (size_t)(i0 + 0) * ND;
    const float* __restrict__ A1 = E + (size_t)(i0 + 1) * ND;
    const float* __restrict__ A2 = E + (size_t)(i0 + 2) * ND;

    // ---- distance, split-k: wave = (h = w/6, jw = w%6); float2 per lane ----
    {
        const int h  = wave / 6;           // k-half
        const int jw = wave % 6;           // j-slice
        const int j0 = jw * 128 + lane * 2;
        const int k0 = h * 64;
        const float2* __restrict__ Bcol = (const float2*)(ET + (size_t)k0 * NB + j0);
        float p0x = 0.f, p0y = 0.f, p1x = 0.f, p1y = 0.f, p2x = 0.f, p2y = 0.f;
        float sjx = 0.f, sjy = 0.f;
        #pragma unroll 16
        for (int kk = 0; kk < 64; ++kk) {
            float2 b = Bcol[(size_t)kk * (NB / 2)];   // coalesced 512 B per instr
            const int k = k0 + kk;
            float a0 = A0[k], a1 = A1[k], a2 = A2[k]; // SGPR broadcasts
            sjx += b.x * b.x; sjy += b.y * b.y;
            p0x += a0 * b.x; p0y += a0 * b.y;
            p1x += a1 * b.x; p1y += a1 * b.y;
            p2x += a2 * b.x; p2y += a2 * b.y;
        }
        *(float2*)&drowp[h][0][j0] = make_float2(sjx - 2.f * p0x, sjy - 2.f * p0y);
        *(float2*)&drowp[h][1][j0] = make_float2(sjx - 2.f * p1x, sjy - 2.f * p1y);
        *(float2*)&drowp[h][2][j0] = make_float2(sjx - 2.f * p2x, sjy - 2.f * p2y);
    }
    __syncthreads();

    // ---- mining, 4-way split: wave = (a = w%3, part = w/3) ----
    {
        const int a    = wave % 3;
        const int part = wave / 3;         // 0..3
        const int ia   = i0 + a;
        const int li   = L[ia];

        // anchor squared norm (coalesced row load + butterfly; wave-uniform)
        float sqa;
        {
            const float* __restrict__ Ar = E + (size_t)ia * ND;
            float v0 = Ar[lane], v1 = Ar[lane + 64];
            float s = v0 * v0 + v1 * v1;
            #pragma unroll
            for (int off = 32; off > 0; off >>= 1) s += __shfl_xor(s, off);
            sqa = s;
        }

        unsigned negm = 0u, posm = 0u;
        float dk[NC];
        #pragma unroll
        for (int c = 0; c < NC; ++c) {
            int j = c * 64 + lane;
            dk[c] = sqrtf(fmaxf(sqa + drowp[0][a][j] + drowp[1][a][j], TL_EPS));
            int lj = L[j];
            if (lj != li)     negm |= (1u << c);
            else if (j != ia) posm |= (1u << c);
        }

        // hardest-negative value (full, duplicated across the 4 parts)
        float bv = INFINITY;
        #pragma unroll
        for (int c = 0; c < NC; ++c)
            if ((negm >> c) & 1u) bv = fminf(bv, dk[c]);
        #pragma unroll
        for (int off = 32; off > 0; off >>= 1)
            bv = fminf(bv, __shfl_xor(bv, off));
        const float hval = bv;

        float lsum = 0.f, lcnt = 0.f;
        if (isfinite(hval)) {
            #pragma unroll
            for (int q = 0; q < 3; ++q) {          // this wave's chunks: part + 4q
                const int c = part + q * 4;
                unsigned long long pm = __ballot((posm >> c) & 1u);
                while (pm) {
                    const int sl = __builtin_ctzll(pm);
                    pm &= pm - 1;
                    const float pd = __shfl(dk[c], sl);
                    float nd = hval;
                    #pragma unroll
                    for (int c2 = 0; c2 < NC; ++c2) {   // full first-k scan
                        bool pred = ((negm >> c2) & 1u) &&
                                    (dk[c2] > pd) && (dk[c2] < pd + TL_MARGIN);
                        unsigned long long m = __ballot(pred);
                        if (m) { nd = __shfl(dk[c2], __builtin_ctzll(m)); break; }
                    }
                    lsum += fmaxf(pd - nd + TL_MARGIN, 0.f);
                    lcnt += 1.f;
                }
            }
        }
        if (lane == 0) { wsum[wave] = lsum; wcnt[wave] = lcnt; }
    }
    __syncthreads();
    if (tid < APB) {
        psum[i0 + tid] = wsum[tid] + wsum[tid + 3] + wsum[tid + 6] + wsum[tid + 9];
        pcnt[i0 + tid] = wcnt[tid] + wcnt[tid + 3] + wcnt[tid + 6] + wcnt[tid + 9];
    }
}

__global__ __launch_bounds__(64) void triplet_finalize_kernel(
    const float* __restrict__ psum, const float* __restrict__ pcnt,
    float* __restrict__ out)
{
    const int lane = threadIdx.x;
    const float4* ps4 = (const float4*)psum;
    const float4* pc4 = (const float4*)pcnt;
    float a = 0.f, b = 0.f;
    #pragma unroll
    for (int r = 0; r < 3; ++r) {          // 192 float4 per array
        float4 x = ps4[lane + r * 64];
        float4 y = pc4[lane + r * 64];
        a += x.x + x.y + x.z + x.w;
        b += y.x + y.y + y.z + y.w;
    }
    #pragma unroll
    for (int off = 32; off > 0; off >>= 1) {
        a += __shfl_xor(a, off);
        b += __shfl_xor(b, off);
    }
    if (lane == 0) out[0] = a / fmaxf(b, 1.f);
}

extern "C" void kernel_launch(void* const* d_in, const int* in_sizes, int n_in,
                              void* d_out, int out_size, void* d_ws, size_t ws_size,
                              hipStream_t stream) {
    const float* E = (const float*)d_in[0];
    const int*   L = (const int*)d_in[1];
    char* ws = (char*)d_ws;
    float* ET   = (float*)(ws);
    float* psum = (float*)(ws + 0x60000);
    float* pcnt = (float*)(ws + 0x60C00);
    float* out  = (float*)d_out;

    transpose_kernel<<<NB * ND / 256, 256, 0, stream>>>(E, ET);
    triplet_fused_kernel<<<NB / APB, NTH, 0, stream>>>(E, ET, L, psum, pcnt);
    triplet_finalize_kernel<<<1, 64, 0, stream>>>(psum, pcnt, out);
}

// Round 15
// 27.158 us; speedup vs baseline: 1.0522x; 1.0522x over previous
//
#include <hip/hip_runtime.h>
#include <math.h>

#define NB 768
#define ND 128
#define NC 12            // NB / 64 lane-chunks (mining layout)
#define APB 3            // anchors per block -> 256 blocks
#define NTH 768          // 12 waves per block
#define TL_MARGIN 1.0f
#define TL_EPS 1e-12f

// ws layout (bytes):
//   ET   @ 0x00000 : 128*768 f32 = 384 KB   (ET[k][j] = E[j][k])
//   psum @ 0x60000 : 768 f32
//   pcnt @ 0x60C00 : 768 f32

// ---- K0: pure transpose, coalesced ET writes; 384 blocks x 256 thr ----
__global__ __launch_bounds__(256) void transpose_kernel(
    const float* __restrict__ E, float* __restrict__ ET)
{
    const int b   = blockIdx.x;           // 0..383
    const int tid = threadIdx.x;
    const int k   = b / 3;                // uniform per block
    const int j   = (b % 3) * 256 + tid;  // lanes consecutive j
    ET[(size_t)k * NB + j] = E[(size_t)j * ND + k];  // write: full coalesced lines
}

// ---- K1: fused distance + mining; 256 blocks x 768 thr (12 waves) ----
__global__ __launch_bounds__(NTH) void triplet_fused_kernel(
    const float* __restrict__ E, const float* __restrict__ ET,
    const int* __restrict__ L,
    float* __restrict__ psum, float* __restrict__ pcnt)
{
    __shared__ float drow[APB][NB];        // 9 KB ; holds sj - 2*dot (pre-sqa)

    const int tid  = threadIdx.x;
    const int lane = tid & 63;
    const int wave = tid >> 6;             // 0..11
    int i0 = blockIdx.x * APB;
    i0 = __builtin_amdgcn_readfirstlane(i0);

    // anchor rows via wave-uniform pointers -> scalar (SGPR) loads
    const float* __restrict__ A0 = E + (size_t)(i0 + 0) * ND;
    const float* __restrict__ A1 = E + (size_t)(i0 + 1) * ND;
    const float* __restrict__ A2 = E + (size_t)(i0 + 2) * ND;

    // mining waves (0..2) privately compute their anchor's squared norm:
    // coalesced 256B row loads + butterfly; result uniform across the wave.
    float sqa = 0.f;
    if (wave < APB) {
        const float* __restrict__ Ar = E + (size_t)(i0 + wave) * ND;
        float v0 = Ar[lane], v1 = Ar[lane + 64];
        float s = v0 * v0 + v1 * v1;
        #pragma unroll
        for (int off = 32; off > 0; off >>= 1) s += __shfl_xor(s, off);
        sqa = s;
    }

    // ---- distance: wave w covers j = w*64 + lane; sj falls out of the stream ----
    {
        const int j = wave * 64 + lane;
        const float* __restrict__ Bcol = ET + j;
        float p0 = 0.f, p1 = 0.f, p2 = 0.f, sjv = 0.f;
        #pragma unroll 16
        for (int k = 0; k < ND; ++k) {
            float b = Bcol[(size_t)k * NB];     // coalesced 256 B per wave-instr
            float a0 = A0[k], a1 = A1[k], a2 = A2[k];   // SGPR broadcasts
            sjv += b * b;
            p0 += a0 * b; p1 += a1 * b; p2 += a2 * b;
        }
        drow[0][j] = sjv - 2.f * p0;
        drow[1][j] = sjv - 2.f * p1;
        drow[2][j] = sjv - 2.f * p2;
    }
    __syncthreads();

    // ---- mining: waves 0..2, wave = anchor (proven code; sqrt at read) ----
    if (wave < APB) {
        const int ia = i0 + wave;
        const int li = L[ia];
        unsigned negm = 0u, posm = 0u;
        float dk[NC];
        #pragma unroll
        for (int c = 0; c < NC; ++c) {
            int j = c * 64 + lane;
            dk[c] = sqrtf(fmaxf(sqa + drow[wave][j], TL_EPS));
            int lj = L[j];
            if (lj != li)     negm |= (1u << c);
            else if (j != ia) posm |= (1u << c);
        }

        float bv = INFINITY;
        #pragma unroll
        for (int c = 0; c < NC; ++c)
            if ((negm >> c) & 1u) bv = fminf(bv, dk[c]);
        #pragma unroll
        for (int off = 32; off > 0; off >>= 1)
            bv = fminf(bv, __shfl_xor(bv, off));
        const float hval = bv;

        float lsum = 0.f, lcnt = 0.f;
        if (isfinite(hval)) {
            #pragma unroll
            for (int c = 0; c < NC; ++c) {
                unsigned long long pm = __ballot((posm >> c) & 1u);
                while (pm) {
                    const int sl = __builtin_ctzll(pm);
                    pm &= pm - 1;
                    const float pd = __shfl(dk[c], sl);
                    float nd = hval;
                    #pragma unroll
                    for (int c2 = 0; c2 < NC; ++c2) {
                        bool pred = ((negm >> c2) & 1u) &&
                                    (dk[c2] > pd) && (dk[c2] < pd + TL_MARGIN);
                        unsigned long long m = __ballot(pred);
                        if (m) { nd = __shfl(dk[c2], __builtin_ctzll(m)); break; }
                    }
                    lsum += fmaxf(pd - nd + TL_MARGIN, 0.f);
                    lcnt += 1.f;
                }
            }
        }
        if (lane == 0) { psum[ia] = lsum; pcnt[ia] = lcnt; }
    }
}

__global__ __launch_bounds__(64) void triplet_finalize_kernel(
    const float* __restrict__ psum, const float* __restrict__ pcnt,
    float* __restrict__ out)
{
    const int lane = threadIdx.x;
    const float4* ps4 = (const float4*)psum;
    const float4* pc4 = (const float4*)pcnt;
    float a = 0.f, b = 0.f;
    #pragma unroll
    for (int r = 0; r < 3; ++r) {          // 192 float4 per array
        float4 x = ps4[lane + r * 64];
        float4 y = pc4[lane + r * 64];
        a += x.x + x.y + x.z + x.w;
        b += y.x + y.y + y.z + y.w;
    }
    #pragma unroll
    for (int off = 32; off > 0; off >>= 1) {
        a += __shfl_xor(a, off);
        b += __shfl_xor(b, off);
    }
    if (lane == 0) out[0] = a / fmaxf(b, 1.f);
}

extern "C" void kernel_launch(void* const* d_in, const int* in_sizes, int n_in,
                              void* d_out, int out_size, void* d_ws, size_t ws_size,
                              hipStream_t stream) {
    const float* E = (const float*)d_in[0];
    const int*   L = (const int*)d_in[1];
    char* ws = (char*)d_ws;
    float* ET   = (float*)(ws);
    float* psum = (float*)(ws + 0x60000);
    float* pcnt = (float*)(ws + 0x60C00);
    float* out  = (float*)d_out;

    transpose_kernel<<<NB * ND / 256, 256, 0, stream>>>(E, ET);
    triplet_fused_kernel<<<NB / APB, NTH, 0, stream>>>(E, ET, L, psum, pcnt);
    triplet_finalize_kernel<<<1, 64, 0, stream>>>(psum, pcnt, out);
}